// Round 2
// baseline (1794.736 us; speedup 1.0000x reference)
//
#include <hip/hip_runtime.h>

#define S_LEN 2048
#define D_DIM 1024
#define H_NUM 16
#define DH 64
#define EPS_GN 1e-5f
#define LAMBDA_INIT 0.8f

typedef unsigned short bfu;

__device__ inline float bf2f(bfu u){
  union { unsigned int i; float f; } c; c.i = ((unsigned int)u) << 16; return c.f;
}
__device__ inline bfu f2bf(float f){
  union { float f; unsigned int u; } c; c.f = f;
  unsigned int r = c.u + 0x7fffu + ((c.u >> 16) & 1u);
  return (bfu)(r >> 16);
}
// dual-dtype scalar load: isf32 selects f32 vs packed-bf16 interpretation
__device__ inline float ldx(const void* p, size_t i, int isf32){
  return isf32 ? ((const float*)p)[i] : bf2f(((const bfu*)p)[i]);
}
__device__ inline float wave_max(float x){
  #pragma unroll
  for (int off = 32; off; off >>= 1) x = fmaxf(x, __shfl_xor(x, off, 64));
  return x;
}
__device__ inline float wave_sum(float x){
  #pragma unroll
  for (int off = 32; off; off >>= 1) x += __shfl_xor(x, off, 64);
  return x;
}

// ---------------- dtype detection ----------------
// gn_w is all-ones. f32: first dword = 0x3F800000. bf16-packed: 0x3F803F80.
__global__ void detect_kernel(const unsigned int* __restrict__ gnw_bits,
                              int* __restrict__ flag){
  if (threadIdx.x == 0) flag[0] = (gnw_bits[0] == 0x3F800000u) ? 1 : 0;
}

// ---------------- lambda per head ----------------
__global__ void lambda_kernel(const void* __restrict__ lq1, const void* __restrict__ lk1,
                              const void* __restrict__ lq2, const void* __restrict__ lk2,
                              const int* __restrict__ flag, float* __restrict__ lam){
  const int isf32 = flag[0];
  int h = threadIdx.x;
  if (h < H_NUM){
    float s1 = 0.f, s2 = 0.f;
    for (int d = 0; d < DH; ++d){
      s1 += ldx(lq1, h*DH+d, isf32) * ldx(lk1, h*DH+d, isf32);
      s2 += ldx(lq2, h*DH+d, isf32) * ldx(lk2, h*DH+d, isf32);
    }
    lam[h] = expf(s1) - expf(s2) + LAMBDA_INIT;
  }
}

// ---------------- fused QKV projection GEMM ----------------
// out[m][n] = sum_k x[m][k]*W[k][n] + b[n];  M=4096, N=K=1024. z selects q/k/v.
__global__ __launch_bounds__(256) void qkv_gemm(
    const void* __restrict__ x,
    const void* __restrict__ Wq, const void* __restrict__ bq,
    const void* __restrict__ Wk, const void* __restrict__ bk,
    const void* __restrict__ Wv, const void* __restrict__ bv,
    const int* __restrict__ flag,
    float* __restrict__ q, float* __restrict__ k, float* __restrict__ v)
{
  const int isf32 = flag[0];
  const void* W; const void* bias; float* out;
  if (blockIdx.z == 0){ W = Wq; bias = bq; out = q; }
  else if (blockIdx.z == 1){ W = Wk; bias = bk; out = k; }
  else { W = Wv; bias = bv; out = v; }

  __shared__ float As[16][64];   // As[kk][m] (transposed A tile)
  __shared__ float Bs[16][64];   // Bs[kk][n]
  const int m0 = blockIdx.x * 64, n0 = blockIdx.y * 64;
  const int t = threadIdx.x;
  const int tm = t >> 4, tn = t & 15;          // 16x16 threads, 4x4 micro-tile
  const int arow = t >> 2, ac = (t & 3) * 4;   // A staging: 64 rows x 16 cols
  const int brow = t >> 4, bc = (t & 15) * 4;  // B staging: 16 rows x 64 cols
  float acc[4][4] = {};

  for (int k0 = 0; k0 < D_DIM; k0 += 16){
    const size_t aoff = (size_t)(m0 + arow) * D_DIM + k0 + ac;
    const size_t boff = (size_t)(k0 + brow) * D_DIM + n0 + bc;
    float a0,a1,a2,a3,b0,b1,b2,b3;
    if (isf32){
      float4 fa = *(const float4*)((const float*)x + aoff);
      float4 fb = *(const float4*)((const float*)W + boff);
      a0=fa.x; a1=fa.y; a2=fa.z; a3=fa.w;
      b0=fb.x; b1=fb.y; b2=fb.z; b3=fb.w;
    } else {
      ushort4 ua = *(const ushort4*)((const bfu*)x + aoff);
      ushort4 ub = *(const ushort4*)((const bfu*)W + boff);
      a0=bf2f(ua.x); a1=bf2f(ua.y); a2=bf2f(ua.z); a3=bf2f(ua.w);
      b0=bf2f(ub.x); b1=bf2f(ub.y); b2=bf2f(ub.z); b3=bf2f(ub.w);
    }
    As[ac+0][arow]=a0; As[ac+1][arow]=a1; As[ac+2][arow]=a2; As[ac+3][arow]=a3;
    Bs[brow][bc+0]=b0; Bs[brow][bc+1]=b1; Bs[brow][bc+2]=b2; Bs[brow][bc+3]=b3;
    __syncthreads();
    #pragma unroll
    for (int kk = 0; kk < 16; ++kk){
      float4 a = *(const float4*)&As[kk][tm*4];
      float4 b = *(const float4*)&Bs[kk][tn*4];
      acc[0][0] += a.x*b.x; acc[0][1] += a.x*b.y; acc[0][2] += a.x*b.z; acc[0][3] += a.x*b.w;
      acc[1][0] += a.y*b.x; acc[1][1] += a.y*b.y; acc[1][2] += a.y*b.z; acc[1][3] += a.y*b.w;
      acc[2][0] += a.z*b.x; acc[2][1] += a.z*b.y; acc[2][2] += a.z*b.z; acc[2][3] += a.z*b.w;
      acc[3][0] += a.w*b.x; acc[3][1] += a.w*b.y; acc[3][2] += a.w*b.z; acc[3][3] += a.w*b.w;
    }
    __syncthreads();
  }
  #pragma unroll
  for (int i = 0; i < 4; ++i){
    size_t m = m0 + tm*4 + i;
    #pragma unroll
    for (int j = 0; j < 4; ++j){
      int n = n0 + tn*4 + j;
      out[m * D_DIM + n] = acc[i][j] + ldx(bias, n, isf32);
    }
  }
}

// ---------------- flash-style differential attention ----------------
// q,k,v: [B,S,H,DH] f32.  o: same layout, o = softmax(q k^T * scale * lam[h]) v
__global__ __launch_bounds__(256) void attn_kernel(
    const float* __restrict__ q, const float* __restrict__ k, const float* __restrict__ v,
    const float* __restrict__ lam, float* __restrict__ o)
{
  __shared__ float Qs[64][64];
  __shared__ float Ks[64][65];   // pitch 65: lane=j scalar reads conflict-free
  __shared__ float Vs[64][64];   // lane=d reads conflict-free
  __shared__ float Ps[4][64][4]; // per-wave P transfer (lane-role j -> d)

  const int b = blockIdx.z, h = blockIdx.y, i0 = blockIdx.x * 64;
  const int t = threadIdx.x, w = t >> 6, lane = t & 63;
  const float sl = 0.125f * lam[h];   // DH^-0.5 = 1/8, lambda folded into Q

  { // stage Q (scaled)
    const int row = t >> 2, c0 = (t & 3) * 16;
    const float* src = q + ((size_t)(b*S_LEN + i0 + row)*H_NUM + h)*DH + c0;
    #pragma unroll
    for (int u = 0; u < 16; u += 4){
      float4 f = *(const float4*)(src + u);
      Qs[row][c0+u+0] = f.x*sl; Qs[row][c0+u+1] = f.y*sl;
      Qs[row][c0+u+2] = f.z*sl; Qs[row][c0+u+3] = f.w*sl;
    }
  }

  float O[16], m_[16], l_[16];
  #pragma unroll
  for (int r = 0; r < 16; ++r){ O[r] = 0.f; m_[r] = -1e30f; l_[r] = 0.f; }

  for (int j0 = 0; j0 < S_LEN; j0 += 64){
    __syncthreads();   // protect K/V tiles from previous iteration's readers
    { // stage K (pitch 65, scalar stores) and V (float4 stores)
      const int row = t >> 2, c0 = (t & 3) * 16;
      const size_t gbase = ((size_t)(b*S_LEN + j0 + row)*H_NUM + h)*DH + c0;
      const float* ksrc = k + gbase;
      const float* vsrc = v + gbase;
      #pragma unroll
      for (int u = 0; u < 16; u += 4){
        float4 f = *(const float4*)(ksrc + u);
        Ks[row][c0+u+0] = f.x; Ks[row][c0+u+1] = f.y;
        Ks[row][c0+u+2] = f.z; Ks[row][c0+u+3] = f.w;
        float4 g = *(const float4*)(vsrc + u);
        *(float4*)&Vs[row][c0+u] = g;
      }
    }
    __syncthreads();

    #pragma unroll 1
    for (int r0 = 0; r0 < 16; r0 += 4){
      // phase 1: lane = j.  scores for 4 rows, 4-d blocked
      float s[4] = {0.f, 0.f, 0.f, 0.f};
      #pragma unroll
      for (int d = 0; d < 64; d += 4){
        float k0_ = Ks[lane][d+0], k1_ = Ks[lane][d+1];
        float k2_ = Ks[lane][d+2], k3_ = Ks[lane][d+3];
        #pragma unroll
        for (int rr = 0; rr < 4; ++rr){
          float4 qv = *(const float4*)&Qs[w*16 + r0 + rr][d];
          s[rr] += qv.x*k0_ + qv.y*k1_ + qv.z*k2_ + qv.w*k3_;
        }
      }
      float p4[4], al4[4];
      #pragma unroll
      for (int rr = 0; rr < 4; ++rr){
        int r = r0 + rr;
        float mt = wave_max(s[rr]);
        float mn = fmaxf(m_[r], mt);
        float pp = __expf(s[rr] - mn);
        float lt = wave_sum(pp);
        float a  = __expf(m_[r] - mn);
        l_[r] = l_[r]*a + lt;
        m_[r] = mn;
        p4[rr] = pp; al4[rr] = a;
      }
      // wave-local P handoff (in-order DS ops within a wave; no barrier needed)
      *(float4*)&Ps[w][lane][0] = make_float4(p4[0], p4[1], p4[2], p4[3]);
      // phase 2: lane = d.  O[r][d] = O*alpha + sum_j p[r][j] * V[j][d]
      float acc[4];
      #pragma unroll
      for (int rr = 0; rr < 4; ++rr) acc[rr] = O[r0+rr] * al4[rr];
      #pragma unroll 8
      for (int j = 0; j < 64; ++j){
        float vv = Vs[j][lane];
        float4 pj = *(const float4*)&Ps[w][j][0];
        acc[0] += pj.x*vv; acc[1] += pj.y*vv; acc[2] += pj.z*vv; acc[3] += pj.w*vv;
      }
      #pragma unroll
      for (int rr = 0; rr < 4; ++rr) O[r0+rr] = acc[rr];
    }
  }

  #pragma unroll
  for (int r = 0; r < 16; ++r){
    int rg = w*16 + r;
    o[((size_t)(b*S_LEN + i0 + rg)*H_NUM + h)*DH + lane] = O[r] / l_[r];
  }
}

// ---------------- GroupNorm stats per (b,h) over (S, DH) ----------------
__global__ __launch_bounds__(256) void gn_stats(const float* __restrict__ o,
                                                float* __restrict__ mean, float* __restrict__ rinv){
  const int bh = blockIdx.x; const int b = bh >> 4, h = bh & 15;
  const float* base = o + ((size_t)b*S_LEN*H_NUM + h)*DH;
  float s1 = 0.f, s2 = 0.f;
  for (int idx = threadIdx.x; idx < S_LEN*DH; idx += 256){
    int s = idx >> 6, d = idx & 63;
    float val = base[(size_t)s * D_DIM + d];
    s1 += val; s2 += val*val;
  }
  s1 = wave_sum(s1); s2 = wave_sum(s2);
  __shared__ float r1[4], r2[4];
  int w = threadIdx.x >> 6, lane = threadIdx.x & 63;
  if (lane == 0){ r1[w] = s1; r2[w] = s2; }
  __syncthreads();
  if (threadIdx.x == 0){
    float S1 = r1[0]+r1[1]+r1[2]+r1[3];
    float S2 = r2[0]+r2[1]+r2[2]+r2[3];
    const float N = (float)(S_LEN*DH);
    float mu = S1 / N;
    float var = S2 / N - mu*mu;
    mean[bh] = mu;
    rinv[bh] = rsqrtf(var + EPS_GN);
  }
}

// ---------------- output projection with fused GroupNorm affine ----------------
__global__ __launch_bounds__(256) void oproj_gemm(
    const float* __restrict__ a,               // attn out [4096][1024] f32
    const void* __restrict__ Wo, const void* __restrict__ bo,
    const float* __restrict__ mean, const float* __restrict__ rinv,
    const void* __restrict__ gnw, const void* __restrict__ gnb,
    const int* __restrict__ flag,
    void* __restrict__ y)
{
  const int isf32 = flag[0];
  __shared__ float As[16][64];
  __shared__ float Bs[16][64];
  const int m0 = blockIdx.x * 64, n0 = blockIdx.y * 64;
  const int t = threadIdx.x;
  const int tm = t >> 4, tn = t & 15;
  const int arow = t >> 2, ac = (t & 3) * 4;
  const int brow = t >> 4, bc = (t & 15) * 4;
  const int b = (m0 + arow) >> 11;   // batch is uniform per block (64 | 2048)
  float acc[4][4] = {};

  for (int k0 = 0; k0 < D_DIM; k0 += 16){
    int cg = k0 + ac;
    int h = cg >> 6;                 // uniform over the 4 staged elements
    float mu = mean[b*H_NUM + h], ri = rinv[b*H_NUM + h];
    float4 av = *(const float4*)(a + (size_t)(m0 + arow) * D_DIM + cg);
    As[ac+0][arow] = (av.x - mu)*ri*ldx(gnw,cg+0,isf32) + ldx(gnb,cg+0,isf32);
    As[ac+1][arow] = (av.y - mu)*ri*ldx(gnw,cg+1,isf32) + ldx(gnb,cg+1,isf32);
    As[ac+2][arow] = (av.z - mu)*ri*ldx(gnw,cg+2,isf32) + ldx(gnb,cg+2,isf32);
    As[ac+3][arow] = (av.w - mu)*ri*ldx(gnw,cg+3,isf32) + ldx(gnb,cg+3,isf32);
    const size_t boff = (size_t)(k0 + brow) * D_DIM + n0 + bc;
    if (isf32){
      float4 fb = *(const float4*)((const float*)Wo + boff);
      Bs[brow][bc+0]=fb.x; Bs[brow][bc+1]=fb.y; Bs[brow][bc+2]=fb.z; Bs[brow][bc+3]=fb.w;
    } else {
      ushort4 ub = *(const ushort4*)((const bfu*)Wo + boff);
      Bs[brow][bc+0]=bf2f(ub.x); Bs[brow][bc+1]=bf2f(ub.y);
      Bs[brow][bc+2]=bf2f(ub.z); Bs[brow][bc+3]=bf2f(ub.w);
    }
    __syncthreads();
    #pragma unroll
    for (int kk = 0; kk < 16; ++kk){
      float4 aa = *(const float4*)&As[kk][tm*4];
      float4 bb = *(const float4*)&Bs[kk][tn*4];
      acc[0][0] += aa.x*bb.x; acc[0][1] += aa.x*bb.y; acc[0][2] += aa.x*bb.z; acc[0][3] += aa.x*bb.w;
      acc[1][0] += aa.y*bb.x; acc[1][1] += aa.y*bb.y; acc[1][2] += aa.y*bb.z; acc[1][3] += aa.y*bb.w;
      acc[2][0] += aa.z*bb.x; acc[2][1] += aa.z*bb.y; acc[2][2] += aa.z*bb.z; acc[2][3] += aa.z*bb.w;
      acc[3][0] += aa.w*bb.x; acc[3][1] += aa.w*bb.y; acc[3][2] += aa.w*bb.z; acc[3][3] += aa.w*bb.w;
    }
    __syncthreads();
  }
  #pragma unroll
  for (int i = 0; i < 4; ++i){
    size_t m = m0 + tm*4 + i;
    #pragma unroll
    for (int j = 0; j < 4; ++j){
      int n = n0 + tn*4 + j;
      float val = acc[i][j] + ldx(bo, n, isf32);
      if (isf32) ((float*)y)[m * D_DIM + n] = val;
      else       ((bfu*)y)[m * D_DIM + n] = f2bf(val);
    }
  }
}

extern "C" void kernel_launch(void* const* d_in, const int* in_sizes, int n_in,
                              void* d_out, int out_size, void* d_ws, size_t ws_size,
                              hipStream_t stream)
{
  const void* x   = d_in[0];
  const void* Wq  = d_in[1];
  const void* bq  = d_in[2];
  const void* Wk  = d_in[3];
  const void* bk  = d_in[4];
  const void* Wv  = d_in[5];
  const void* bv  = d_in[6];
  const void* Wo  = d_in[7];
  const void* bo  = d_in[8];
  const void* lq1 = d_in[9];
  const void* lk1 = d_in[10];
  const void* lq2 = d_in[11];
  const void* lk2 = d_in[12];
  const void* gnw = d_in[13];
  const void* gnb = d_in[14];

  float* ws   = (float*)d_ws;
  int*   flag = (int*)d_ws;  // 1 int (first 16-float slot reserved)
  float* lam  = ws + 16;     // 16 floats
  float* mean = ws + 48;     // 32 floats
  float* rinv = ws + 80;     // 32 floats
  float* q    = ws + 128;    // 4 x 4194304 floats follow
  float* k    = q + (size_t)4194304;
  float* v    = k + (size_t)4194304;
  float* o    = v + (size_t)4194304;

  detect_kernel<<<1, 64, 0, stream>>>((const unsigned int*)gnw, flag);
  lambda_kernel<<<1, 64, 0, stream>>>(lq1, lk1, lq2, lk2, flag, lam);
  qkv_gemm<<<dim3(64, 16, 3), 256, 0, stream>>>(x, Wq, bq, Wk, bk, Wv, bv, flag, q, k, v);
  attn_kernel<<<dim3(32, 16, 2), 256, 0, stream>>>(q, k, v, lam, o);
  gn_stats<<<32, 256, 0, stream>>>(o, mean, rinv);
  oproj_gemm<<<dim3(64, 16), 256, 0, stream>>>(o, Wo, bo, mean, rinv, gnw, gnb, flag, d_out);
}

// Round 3
// 391.810 us; speedup vs baseline: 4.5806x; 4.5806x over previous
//
#include <hip/hip_runtime.h>

#define S_LEN 2048
#define D_DIM 1024
#define H_NUM 16
#define DH 64
#define EPS_GN 1e-5f
#define LAMBDA_INIT 0.8f

typedef unsigned short bfu;
typedef __attribute__((ext_vector_type(8))) short bf16x8;
typedef __attribute__((ext_vector_type(4))) float f32x4;

union FragU { uint4 u; bf16x8 f; };

__device__ inline float bf2f(bfu u){
  union { unsigned int i; float f; } c; c.i = ((unsigned int)u) << 16; return c.f;
}
__device__ inline bfu f2bf(float f){
  union { float f; unsigned int u; } c; c.f = f;
  unsigned int r = c.u + 0x7fffu + ((c.u >> 16) & 1u);
  return (bfu)(r >> 16);
}
__device__ inline float ldx(const void* p, size_t i, int isf32){
  return isf32 ? ((const float*)p)[i] : bf2f(((const bfu*)p)[i]);
}
__device__ inline float wave_sum(float x){
  #pragma unroll
  for (int off = 32; off; off >>= 1) x += __shfl_xor(x, off, 64);
  return x;
}
// reduce within 16-lane groups (rows are quad-local in MFMA C layout)
__device__ inline float qmax(float x){
  #pragma unroll
  for (int off = 1; off < 16; off <<= 1) x = fmaxf(x, __shfl_xor(x, off, 64));
  return x;
}
__device__ inline float qsum(float x){
  #pragma unroll
  for (int off = 1; off < 16; off <<= 1) x += __shfl_xor(x, off, 64);
  return x;
}

// ---------------- dtype detection (gn_w all-ones) ----------------
__global__ void detect_kernel(const unsigned int* __restrict__ gnw_bits, int* __restrict__ flag){
  if (threadIdx.x == 0) flag[0] = (gnw_bits[0] == 0x3F800000u) ? 1 : 0;
}

// ---------------- lambda per head ----------------
__global__ void lambda_kernel(const void* __restrict__ lq1, const void* __restrict__ lk1,
                              const void* __restrict__ lq2, const void* __restrict__ lk2,
                              const int* __restrict__ flag, float* __restrict__ lam){
  const int isf32 = flag[0];
  int h = threadIdx.x;
  if (h < H_NUM){
    float s1 = 0.f, s2 = 0.f;
    for (int d = 0; d < DH; ++d){
      s1 += ldx(lq1, h*DH+d, isf32) * ldx(lk1, h*DH+d, isf32);
      s2 += ldx(lq2, h*DH+d, isf32) * ldx(lk2, h*DH+d, isf32);
    }
    lam[h] = expf(s1) - expf(s2) + LAMBDA_INIT;
  }
}

// ---------------- x -> bf16 canonical ----------------
__global__ __launch_bounds__(256) void prep_x(const void* __restrict__ x,
                                              const int* __restrict__ flag,
                                              bfu* __restrict__ xb){
  const int isf32 = flag[0];
  size_t i = ((size_t)blockIdx.x * 256 + threadIdx.x) * 8;
  if (isf32){
    const float* xf = (const float*)x;
    float4 a = *(const float4*)(xf + i);
    float4 b = *(const float4*)(xf + i + 4);
    bfu o[8] = {f2bf(a.x),f2bf(a.y),f2bf(a.z),f2bf(a.w),f2bf(b.x),f2bf(b.y),f2bf(b.z),f2bf(b.w)};
    *(uint4*)(xb + i) = *(const uint4*)o;
  } else {
    *(uint4*)(xb + i) = *(const uint4*)((const bfu*)x + i);
  }
}

// ---------------- W [k][n] -> Wt [n][k] bf16 ----------------
__global__ __launch_bounds__(256) void prep_w(const void* __restrict__ w0, const void* __restrict__ w1,
                                              const void* __restrict__ w2, const void* __restrict__ w3,
                                              const int* __restrict__ flag, bfu* __restrict__ wt){
  const int isf32 = flag[0];
  const void* W = (blockIdx.z==0)?w0:(blockIdx.z==1)?w1:(blockIdx.z==2)?w2:w3;
  bfu* dst = wt + (size_t)blockIdx.z * D_DIM * D_DIM;
  __shared__ float Ts[64][65];
  const int r0 = blockIdx.x * 64, c0 = blockIdx.y * 64;
  const int ty = threadIdx.x >> 6, tx = threadIdx.x & 63;
  #pragma unroll
  for (int rr = 0; rr < 16; ++rr){
    int row = ty*16 + rr;
    Ts[row][tx] = ldx(W, (size_t)(r0 + row) * D_DIM + c0 + tx, isf32);
  }
  __syncthreads();
  #pragma unroll
  for (int rr = 0; rr < 16; ++rr){
    int row = ty*16 + rr;   // row within transposed tile = original col
    dst[(size_t)(c0 + row) * D_DIM + r0 + tx] = f2bf(Ts[tx][row]);
  }
}

// ---------------- QKV projection: bf16 MFMA GEMM 128x128, BK=32 ----------------
// xb [M=4096][K=1024], Wt [n][k].  q/k out: bf16 [B,S,H,DH]; v out transposed [B,H,DH,S].
__global__ __launch_bounds__(256) void qkv_mfma(
    const bfu* __restrict__ xb, const bfu* __restrict__ wt,
    const void* __restrict__ bq, const void* __restrict__ bk, const void* __restrict__ bv,
    const int* __restrict__ flag,
    bfu* __restrict__ qb, bfu* __restrict__ kb, bfu* __restrict__ vt)
{
  const int isf32 = flag[0];
  const int z = blockIdx.z;
  const bfu* Wt = wt + (size_t)z * D_DIM * D_DIM;
  const void* bias = (z==0)?bq:(z==1)?bk:bv;

  __shared__ __align__(16) ushort As[128][40];
  __shared__ __align__(16) ushort Bs[128][40];
  const int m0 = blockIdx.x * 128, n0 = blockIdx.y * 128;
  const int t = threadIdx.x, w = t >> 6, lane = t & 63;
  const int quad = lane >> 4, l15 = lane & 15;
  const int mbase = (w >> 1) * 64, nbase = (w & 1) * 64;
  const int srow = t >> 1, shalf = (t & 1) * 16;

  f32x4 acc[4][4];
  #pragma unroll
  for (int i = 0; i < 4; ++i)
    #pragma unroll
    for (int j = 0; j < 4; ++j){ f32x4 zz = {0.f,0.f,0.f,0.f}; acc[i][j] = zz; }

  for (int k0 = 0; k0 < D_DIM; k0 += 32){
    const bfu* asrc = xb + (size_t)(m0 + srow) * D_DIM + k0 + shalf;
    const bfu* bsrc = Wt + (size_t)(n0 + srow) * D_DIM + k0 + shalf;
    uint4 a0 = *(const uint4*)asrc, a1 = *(const uint4*)(asrc + 8);
    uint4 b0 = *(const uint4*)bsrc, b1 = *(const uint4*)(bsrc + 8);
    *(uint4*)&As[srow][shalf]     = a0;  *(uint4*)&As[srow][shalf + 8] = a1;
    *(uint4*)&Bs[srow][shalf]     = b0;  *(uint4*)&Bs[srow][shalf + 8] = b1;
    __syncthreads();
    FragU af[4], bf[4];
    #pragma unroll
    for (int mt = 0; mt < 4; ++mt) af[mt].u = *(const uint4*)&As[mbase + mt*16 + l15][quad*8];
    #pragma unroll
    for (int nt = 0; nt < 4; ++nt) bf[nt].u = *(const uint4*)&Bs[nbase + nt*16 + l15][quad*8];
    #pragma unroll
    for (int mt = 0; mt < 4; ++mt)
      #pragma unroll
      for (int nt = 0; nt < 4; ++nt)
        acc[mt][nt] = __builtin_amdgcn_mfma_f32_16x16x32_bf16(af[mt].f, bf[nt].f, acc[mt][nt], 0, 0, 0);
    __syncthreads();
  }

  // epilogue: C row = quad*4+reg, col = l15
  #pragma unroll
  for (int mt = 0; mt < 4; ++mt){
    const int mrow = m0 + mbase + mt*16 + quad*4;
    #pragma unroll
    for (int nt = 0; nt < 4; ++nt){
      const int n = n0 + nbase + nt*16 + l15;
      const float bn = ldx(bias, n, isf32);
      if (z < 2){
        bfu* out = (z == 0) ? qb : kb;
        #pragma unroll
        for (int r = 0; r < 4; ++r)
          out[(size_t)(mrow + r) * D_DIM + n] = f2bf(acc[mt][nt][r] + bn);
      } else {
        // vt[((b*H + h)*DH + d)*S + s], 4 regs = 4 consecutive s
        const int b = mrow >> 11, s = mrow & (S_LEN - 1);
        const int h = n >> 6, d = n & 63;
        ushort4 pk;
        pk.x = f2bf(acc[mt][nt][0] + bn); pk.y = f2bf(acc[mt][nt][1] + bn);
        pk.z = f2bf(acc[mt][nt][2] + bn); pk.w = f2bf(acc[mt][nt][3] + bn);
        *(ushort4*)(vt + (((size_t)(b*H_NUM + h)*DH + d)*S_LEN) + s) = pk;
      }
    }
  }
}

// ---------------- MFMA flash attention ----------------
// qb,kb bf16 [B,S,H,DH]; vt bf16 [B,H,DH,S]; o bf16 [B,S,H,DH]
__global__ __launch_bounds__(256) void attn_mfma(
    const bfu* __restrict__ qb, const bfu* __restrict__ kb, const bfu* __restrict__ vt,
    const float* __restrict__ lam, bfu* __restrict__ o)
{
  __shared__ __align__(16) ushort Ks[64][72];      // [j][d]
  __shared__ __align__(16) ushort Vs[64][72];      // [d][j]
  __shared__ __align__(16) ushort Ps[4][16][72];   // per-wave P [i][j]

  const int b = blockIdx.z, h = blockIdx.y, i0 = blockIdx.x * 64;
  const int t = threadIdx.x, w = t >> 6, lane = t & 63;
  const int quad = lane >> 4, l15 = lane & 15;
  const float sl = 0.125f * lam[h];

  // Q fragments (A layout: m=l15, k=quad*8+j), 2 chunks over d
  FragU qf[2];
  {
    const bfu* qrow = qb + ((size_t)(b*S_LEN + i0 + w*16 + l15)*H_NUM + h)*DH;
    qf[0].u = *(const uint4*)(qrow + quad*8);
    qf[1].u = *(const uint4*)(qrow + 32 + quad*8);
  }

  f32x4 Oacc[4];
  #pragma unroll
  for (int nt = 0; nt < 4; ++nt){ f32x4 zz = {0.f,0.f,0.f,0.f}; Oacc[nt] = zz; }
  float m_[4], l_[4];
  #pragma unroll
  for (int r = 0; r < 4; ++r){ m_[r] = -1e30f; l_[r] = 0.f; }

  const int srow = t >> 2, scg = (t & 3) * 16;

  for (int j0 = 0; j0 < S_LEN; j0 += 64){
    __syncthreads();
    { // stage K [j][d] and V [d][j]
      const bfu* ksrc = kb + ((size_t)(b*S_LEN + j0 + srow)*H_NUM + h)*DH + scg;
      const bfu* vsrc = vt + ((size_t)(b*H_NUM + h)*DH + srow)*S_LEN + j0 + scg;
      uint4 k0v = *(const uint4*)ksrc, k1v = *(const uint4*)(ksrc + 8);
      uint4 v0v = *(const uint4*)vsrc, v1v = *(const uint4*)(vsrc + 8);
      *(uint4*)&Ks[srow][scg]     = k0v;  *(uint4*)&Ks[srow][scg + 8] = k1v;
      *(uint4*)&Vs[srow][scg]     = v0v;  *(uint4*)&Vs[srow][scg + 8] = v1v;
    }
    __syncthreads();

    // QK^T: s[jt] covers j = jt*16 + l15, rows i = quad*4 + r
    f32x4 s[4];
    #pragma unroll
    for (int jt = 0; jt < 4; ++jt){
      FragU kf0, kf1;
      kf0.u = *(const uint4*)&Ks[jt*16 + l15][quad*8];
      kf1.u = *(const uint4*)&Ks[jt*16 + l15][32 + quad*8];
      f32x4 zz = {0.f,0.f,0.f,0.f};
      zz = __builtin_amdgcn_mfma_f32_16x16x32_bf16(qf[0].f, kf0.f, zz, 0, 0, 0);
      zz = __builtin_amdgcn_mfma_f32_16x16x32_bf16(qf[1].f, kf1.f, zz, 0, 0, 0);
      #pragma unroll
      for (int r = 0; r < 4; ++r) zz[r] *= sl;
      s[jt] = zz;
    }

    // online softmax per row (rows are quad-local: reduce over 16 lanes)
    float al[4];
    #pragma unroll
    for (int r = 0; r < 4; ++r){
      float mt_ = fmaxf(fmaxf(s[0][r], s[1][r]), fmaxf(s[2][r], s[3][r]));
      mt_ = qmax(mt_);
      float mn = fmaxf(m_[r], mt_);
      float a  = __expf(m_[r] - mn);
      float lt = 0.f;
      #pragma unroll
      for (int jt = 0; jt < 4; ++jt){
        float p = __expf(s[jt][r] - mn);
        s[jt][r] = p;
        lt += p;
      }
      lt = qsum(lt);
      l_[r] = l_[r]*a + lt;
      m_[r] = mn;
      al[r] = a;
    }

    // P C-layout -> A-layout via per-wave LDS (wave-local, in-order DS)
    #pragma unroll
    for (int jt = 0; jt < 4; ++jt)
      #pragma unroll
      for (int r = 0; r < 4; ++r)
        Ps[w][quad*4 + r][jt*16 + l15] = f2bf(s[jt][r]);

    FragU pf0, pf1;
    pf0.u = *(const uint4*)&Ps[w][l15][quad*8];
    pf1.u = *(const uint4*)&Ps[w][l15][32 + quad*8];

    // rescale O, then PV
    #pragma unroll
    for (int nt = 0; nt < 4; ++nt)
      #pragma unroll
      for (int r = 0; r < 4; ++r) Oacc[nt][r] *= al[r];
    #pragma unroll
    for (int nt = 0; nt < 4; ++nt){
      FragU vf0, vf1;
      vf0.u = *(const uint4*)&Vs[nt*16 + l15][quad*8];
      vf1.u = *(const uint4*)&Vs[nt*16 + l15][32 + quad*8];
      Oacc[nt] = __builtin_amdgcn_mfma_f32_16x16x32_bf16(pf0.f, vf0.f, Oacc[nt], 0, 0, 0);
      Oacc[nt] = __builtin_amdgcn_mfma_f32_16x16x32_bf16(pf1.f, vf1.f, Oacc[nt], 0, 0, 0);
    }
  }

  float inv[4];
  #pragma unroll
  for (int r = 0; r < 4; ++r) inv[r] = 1.f / l_[r];
  #pragma unroll
  for (int nt = 0; nt < 4; ++nt)
    #pragma unroll
    for (int r = 0; r < 4; ++r){
      size_t idx = ((size_t)(b*S_LEN + i0 + w*16 + quad*4 + r)*H_NUM + h)*DH + nt*16 + l15;
      o[idx] = f2bf(Oacc[nt][r] * inv[r]);
    }
}

// ---------------- GroupNorm stats per (b,h) over (S, DH) ----------------
__global__ __launch_bounds__(256) void gn_stats(const bfu* __restrict__ o,
                                                float* __restrict__ mean, float* __restrict__ rinv){
  const int bh = blockIdx.x; const int b = bh >> 4, h = bh & 15;
  const bfu* base = o + ((size_t)b*S_LEN*H_NUM + h)*DH;
  float s1 = 0.f, s2 = 0.f;
  for (int u = threadIdx.x*4; u < S_LEN*DH; u += 256*4){
    int s = u >> 6, d = u & 63;
    ushort4 p = *(const ushort4*)(base + (size_t)s * D_DIM + d);
    float v0 = bf2f(p.x), v1 = bf2f(p.y), v2 = bf2f(p.z), v3 = bf2f(p.w);
    s1 += v0+v1+v2+v3; s2 += v0*v0+v1*v1+v2*v2+v3*v3;
  }
  s1 = wave_sum(s1); s2 = wave_sum(s2);
  __shared__ float r1[4], r2[4];
  int w = threadIdx.x >> 6, lane = threadIdx.x & 63;
  if (lane == 0){ r1[w] = s1; r2[w] = s2; }
  __syncthreads();
  if (threadIdx.x == 0){
    float S1 = r1[0]+r1[1]+r1[2]+r1[3];
    float S2 = r2[0]+r2[1]+r2[2]+r2[3];
    const float N = (float)(S_LEN*DH);
    float mu = S1 / N;
    float var = S2 / N - mu*mu;
    mean[bh] = mu;
    rinv[bh] = rsqrtf(var + EPS_GN);
  }
}

// ---------------- output projection MFMA with fused GroupNorm affine ----------------
__global__ __launch_bounds__(256) void oproj_mfma(
    const bfu* __restrict__ o, const bfu* __restrict__ wt,   // wt = Wo^T at offset
    const void* __restrict__ bo,
    const float* __restrict__ mean, const float* __restrict__ rinv,
    const void* __restrict__ gnw, const void* __restrict__ gnb,
    const int* __restrict__ flag, void* __restrict__ y)
{
  const int isf32 = flag[0];
  __shared__ __align__(16) ushort As[128][40];
  __shared__ __align__(16) ushort Bs[128][40];
  const int m0 = blockIdx.x * 128, n0 = blockIdx.y * 128;
  const int t = threadIdx.x, w = t >> 6, lane = t & 63;
  const int quad = lane >> 4, l15 = lane & 15;
  const int mbase = (w >> 1) * 64, nbase = (w & 1) * 64;
  const int srow = t >> 1, shalf = (t & 1) * 16;

  f32x4 acc[4][4];
  #pragma unroll
  for (int i = 0; i < 4; ++i)
    #pragma unroll
    for (int j = 0; j < 4; ++j){ f32x4 zz = {0.f,0.f,0.f,0.f}; acc[i][j] = zz; }

  const int bB = (m0 + srow) >> 11;

  for (int k0 = 0; k0 < D_DIM; k0 += 32){
    { // A: normed o -> bf16
      const int kg = k0 + shalf;
      const int hh = kg >> 6;                  // uniform over 16 staged cols
      const float mu = mean[bB*H_NUM + hh], ri = rinv[bB*H_NUM + hh];
      const bfu* asrc = o + (size_t)(m0 + srow) * D_DIM + kg;
      uint4 a0 = *(const uint4*)asrc, a1 = *(const uint4*)(asrc + 8);
      const bfu* ap = (const bfu*)&a0;
      bfu tmp[16];
      #pragma unroll
      for (int j = 0; j < 8; ++j)
        tmp[j] = f2bf((bf2f(ap[j]) - mu)*ri*ldx(gnw, kg+j, isf32) + ldx(gnb, kg+j, isf32));
      const bfu* ap2 = (const bfu*)&a1;
      #pragma unroll
      for (int j = 0; j < 8; ++j)
        tmp[8+j] = f2bf((bf2f(ap2[j]) - mu)*ri*ldx(gnw, kg+8+j, isf32) + ldx(gnb, kg+8+j, isf32));
      *(uint4*)&As[srow][shalf]     = *(const uint4*)tmp;
      *(uint4*)&As[srow][shalf + 8] = *(const uint4*)(tmp + 8);
    }
    {
      const bfu* bsrc = wt + (size_t)(n0 + srow) * D_DIM + k0 + shalf;
      uint4 b0 = *(const uint4*)bsrc, b1 = *(const uint4*)(bsrc + 8);
      *(uint4*)&Bs[srow][shalf]     = b0;  *(uint4*)&Bs[srow][shalf + 8] = b1;
    }
    __syncthreads();
    FragU af[4], bf[4];
    #pragma unroll
    for (int mt = 0; mt < 4; ++mt) af[mt].u = *(const uint4*)&As[mbase + mt*16 + l15][quad*8];
    #pragma unroll
    for (int nt = 0; nt < 4; ++nt) bf[nt].u = *(const uint4*)&Bs[nbase + nt*16 + l15][quad*8];
    #pragma unroll
    for (int mt = 0; mt < 4; ++mt)
      #pragma unroll
      for (int nt = 0; nt < 4; ++nt)
        acc[mt][nt] = __builtin_amdgcn_mfma_f32_16x16x32_bf16(af[mt].f, bf[nt].f, acc[mt][nt], 0, 0, 0);
    __syncthreads();
  }

  #pragma unroll
  for (int mt = 0; mt < 4; ++mt){
    const int mrow = m0 + mbase + mt*16 + quad*4;
    #pragma unroll
    for (int nt = 0; nt < 4; ++nt){
      const int n = n0 + nbase + nt*16 + l15;
      const float bn = ldx(bo, n, isf32);
      #pragma unroll
      for (int r = 0; r < 4; ++r){
        float val = acc[mt][nt][r] + bn;
        if (isf32) ((float*)y)[(size_t)(mrow + r) * D_DIM + n] = val;
        else       ((bfu*)y)[(size_t)(mrow + r) * D_DIM + n] = f2bf(val);
      }
    }
  }
}

extern "C" void kernel_launch(void* const* d_in, const int* in_sizes, int n_in,
                              void* d_out, int out_size, void* d_ws, size_t ws_size,
                              hipStream_t stream)
{
  const void* x   = d_in[0];
  const void* Wq  = d_in[1];
  const void* bq  = d_in[2];
  const void* Wk  = d_in[3];
  const void* bk  = d_in[4];
  const void* Wv  = d_in[5];
  const void* bv  = d_in[6];
  const void* Wo  = d_in[7];
  const void* bo  = d_in[8];
  const void* lq1 = d_in[9];
  const void* lk1 = d_in[10];
  const void* lq2 = d_in[11];
  const void* lk2 = d_in[12];
  const void* gnw = d_in[13];
  const void* gnb = d_in[14];

  float* ws   = (float*)d_ws;
  int*   flag = (int*)d_ws;
  float* lam  = ws + 16;
  float* mean = ws + 48;
  float* rinv = ws + 80;

  const size_t MB = 1u << 20;
  char* base = (char*)d_ws + 4096;
  bfu* xb = (bfu*)(base);             // 8 MB
  bfu* wt = (bfu*)(base + 8*MB);      // 8 MB (Wq^T, Wk^T, Wv^T, Wo^T)
  bfu* qb = (bfu*)(base + 16*MB);     // 8 MB
  bfu* kb = (bfu*)(base + 24*MB);     // 8 MB
  bfu* vt = (bfu*)(base + 32*MB);     // 8 MB  [B,H,DH,S]
  bfu* ob = (bfu*)(base + 40*MB);     // 8 MB

  detect_kernel<<<1, 64, 0, stream>>>((const unsigned int*)gnw, flag);
  lambda_kernel<<<1, 64, 0, stream>>>(lq1, lk1, lq2, lk2, flag, lam);
  prep_x<<<2048, 256, 0, stream>>>(x, flag, xb);
  prep_w<<<dim3(16, 16, 4), 256, 0, stream>>>(Wq, Wk, Wv, Wo, flag, wt);
  qkv_mfma<<<dim3(32, 8, 3), 256, 0, stream>>>(xb, wt, bq, bk, bv, flag, qb, kb, vt);
  attn_mfma<<<dim3(32, 16, 2), 256, 0, stream>>>(qb, kb, vt, lam, ob);
  gn_stats<<<32, 256, 0, stream>>>(ob, mean, rinv);
  oproj_mfma<<<dim3(32, 8), 256, 0, stream>>>(ob, wt + (size_t)3*D_DIM*D_DIM, bo, mean, rinv, gnw, gnb, flag, d_out);
}

// Round 4
// 352.145 us; speedup vs baseline: 5.0966x; 1.1126x over previous
//
#include <hip/hip_runtime.h>

#define S_LEN 2048
#define D_DIM 1024
#define H_NUM 16
#define DH 64
#define EPS_GN 1e-5f
#define LAMBDA_INIT 0.8f

typedef unsigned short bfu;
typedef __attribute__((ext_vector_type(8))) short bf16x8;
typedef __attribute__((ext_vector_type(4))) float f32x4;

union FragU { uint4 u; bf16x8 f; };

__device__ inline float bf2f(bfu u){
  union { unsigned int i; float f; } c; c.i = ((unsigned int)u) << 16; return c.f;
}
__device__ inline bfu f2bf(float f){
  union { float f; unsigned int u; } c; c.f = f;
  unsigned int r = c.u + 0x7fffu + ((c.u >> 16) & 1u);
  return (bfu)(r >> 16);
}
__device__ inline float ldx(const void* p, size_t i, int isf32){
  return isf32 ? ((const float*)p)[i] : bf2f(((const bfu*)p)[i]);
}
__device__ inline float wave_sum(float x){
  #pragma unroll
  for (int off = 32; off; off >>= 1) x += __shfl_xor(x, off, 64);
  return x;
}

// ---------------- lambda + dtype flag + zero GN sums ----------------
__global__ void lambda_kernel(const void* __restrict__ lq1, const void* __restrict__ lk1,
                              const void* __restrict__ lq2, const void* __restrict__ lk2,
                              const unsigned int* __restrict__ gnw_bits,
                              int* __restrict__ flag, float* __restrict__ lam,
                              float* __restrict__ sums){
  const int isf32 = (gnw_bits[0] == 0x3F800000u) ? 1 : 0;
  int t = threadIdx.x;
  if (t == 0) flag[0] = isf32;
  sums[t] = 0.f;                       // 64 floats: 32 (b,h) x {s1,s2}
  if (t < H_NUM){
    float s1 = 0.f, s2 = 0.f;
    for (int d = 0; d < DH; ++d){
      s1 += ldx(lq1, t*DH+d, isf32) * ldx(lk1, t*DH+d, isf32);
      s2 += ldx(lq2, t*DH+d, isf32) * ldx(lk2, t*DH+d, isf32);
    }
    lam[t] = expf(s1) - expf(s2) + LAMBDA_INIT;
  }
}

// ---------------- fused prep: x->bf16 (blocks 0..2047), W^T (blocks 2048..3071) ----------------
__global__ __launch_bounds__(256) void prep_all(
    const void* __restrict__ x,
    const void* __restrict__ w0, const void* __restrict__ w1,
    const void* __restrict__ w2, const void* __restrict__ w3,
    const int* __restrict__ flag, bfu* __restrict__ xb, bfu* __restrict__ wt)
{
  const int isf32 = flag[0];
  if (blockIdx.x < 2048){
    size_t i = ((size_t)blockIdx.x * 256 + threadIdx.x) * 8;
    if (isf32){
      const float* xf = (const float*)x;
      float4 a = *(const float4*)(xf + i);
      float4 b = *(const float4*)(xf + i + 4);
      bfu o[8] = {f2bf(a.x),f2bf(a.y),f2bf(a.z),f2bf(a.w),f2bf(b.x),f2bf(b.y),f2bf(b.z),f2bf(b.w)};
      *(uint4*)(xb + i) = *(const uint4*)o;
    } else {
      *(uint4*)(xb + i) = *(const uint4*)((const bfu*)x + i);
    }
    return;
  }
  const int widx = blockIdx.x - 2048;
  const int wsel = widx >> 8, tile = widx & 255;
  const void* W = (wsel==0)?w0:(wsel==1)?w1:(wsel==2)?w2:w3;
  bfu* dst = wt + (size_t)wsel * D_DIM * D_DIM;
  __shared__ float Ts[64][65];
  const int r0 = (tile >> 4) * 64, c0 = (tile & 15) * 64;
  const int ty = threadIdx.x >> 6, tx = threadIdx.x & 63;
  #pragma unroll
  for (int rr = 0; rr < 16; ++rr){
    int row = ty*16 + rr;
    Ts[row][tx] = ldx(W, (size_t)(r0 + row) * D_DIM + c0 + tx, isf32);
  }
  __syncthreads();
  #pragma unroll
  for (int rr = 0; rr < 16; ++rr){
    int row = ty*16 + rr;
    dst[(size_t)(c0 + row) * D_DIM + r0 + tx] = f2bf(Ts[tx][row]);
  }
}

// ---------------- QKV projection: bf16 MFMA GEMM 128x128, BK=32 ----------------
__global__ __launch_bounds__(256) void qkv_mfma(
    const bfu* __restrict__ xb, const bfu* __restrict__ wt,
    const void* __restrict__ bq, const void* __restrict__ bk, const void* __restrict__ bv,
    const int* __restrict__ flag,
    bfu* __restrict__ qb, bfu* __restrict__ kb, bfu* __restrict__ vt)
{
  const int isf32 = flag[0];
  const int z = blockIdx.z;
  const bfu* Wt = wt + (size_t)z * D_DIM * D_DIM;
  const void* bias = (z==0)?bq:(z==1)?bk:bv;

  __shared__ __align__(16) ushort As[128][40];
  __shared__ __align__(16) ushort Bs[128][40];
  const int m0 = blockIdx.x * 128, n0 = blockIdx.y * 128;
  const int t = threadIdx.x, w = t >> 6, lane = t & 63;
  const int quad = lane >> 4, l15 = lane & 15;
  const int mbase = (w >> 1) * 64, nbase = (w & 1) * 64;
  const int srow = t >> 1, shalf = (t & 1) * 16;

  f32x4 acc[4][4];
  #pragma unroll
  for (int i = 0; i < 4; ++i)
    #pragma unroll
    for (int j = 0; j < 4; ++j){ f32x4 zz = {0.f,0.f,0.f,0.f}; acc[i][j] = zz; }

  for (int k0 = 0; k0 < D_DIM; k0 += 32){
    const bfu* asrc = xb + (size_t)(m0 + srow) * D_DIM + k0 + shalf;
    const bfu* bsrc = Wt + (size_t)(n0 + srow) * D_DIM + k0 + shalf;
    uint4 a0 = *(const uint4*)asrc, a1 = *(const uint4*)(asrc + 8);
    uint4 b0 = *(const uint4*)bsrc, b1 = *(const uint4*)(bsrc + 8);
    *(uint4*)&As[srow][shalf]     = a0;  *(uint4*)&As[srow][shalf + 8] = a1;
    *(uint4*)&Bs[srow][shalf]     = b0;  *(uint4*)&Bs[srow][shalf + 8] = b1;
    __syncthreads();
    FragU af[4], bf[4];
    #pragma unroll
    for (int mt = 0; mt < 4; ++mt) af[mt].u = *(const uint4*)&As[mbase + mt*16 + l15][quad*8];
    #pragma unroll
    for (int nt = 0; nt < 4; ++nt) bf[nt].u = *(const uint4*)&Bs[nbase + nt*16 + l15][quad*8];
    #pragma unroll
    for (int mt = 0; mt < 4; ++mt)
      #pragma unroll
      for (int nt = 0; nt < 4; ++nt)
        acc[mt][nt] = __builtin_amdgcn_mfma_f32_16x16x32_bf16(af[mt].f, bf[nt].f, acc[mt][nt], 0, 0, 0);
    __syncthreads();
  }

  #pragma unroll
  for (int mt = 0; mt < 4; ++mt){
    const int mrow = m0 + mbase + mt*16 + quad*4;
    #pragma unroll
    for (int nt = 0; nt < 4; ++nt){
      const int n = n0 + nbase + nt*16 + l15;
      const float bn = ldx(bias, n, isf32);
      if (z < 2){
        bfu* out = (z == 0) ? qb : kb;
        #pragma unroll
        for (int r = 0; r < 4; ++r)
          out[(size_t)(mrow + r) * D_DIM + n] = f2bf(acc[mt][nt][r] + bn);
      } else {
        const int b = mrow >> 11, s = mrow & (S_LEN - 1);
        const int h = n >> 6, d = n & 63;
        ushort4 pk;
        pk.x = f2bf(acc[mt][nt][0] + bn); pk.y = f2bf(acc[mt][nt][1] + bn);
        pk.z = f2bf(acc[mt][nt][2] + bn); pk.w = f2bf(acc[mt][nt][3] + bn);
        *(ushort4*)(vt + (((size_t)(b*H_NUM + h)*DH + d)*S_LEN) + s) = pk;
      }
    }
  }
}

// ---------------- transposed-S MFMA flash attention (no barriers) ----------------
// S^T = K·Q^T: C-layout gives each lane 16 scores of ONE Q-row -> lane-local softmax state.
// K and V^T fragments read directly from global (L1/L2-resident tiles). LDS only for P.
__global__ __launch_bounds__(256, 2) void attn_mfma(
    const bfu* __restrict__ qb, const bfu* __restrict__ kb, const bfu* __restrict__ vt,
    const float* __restrict__ lam, bfu* __restrict__ o)
{
  __shared__ __align__(16) ushort Ps[4][2][16][72];   // [wave][mt][m][j]

  const int b = blockIdx.z, h = blockIdx.y, i0 = blockIdx.x * 128;
  const int t = threadIdx.x, w = t >> 6, lane = t & 63;
  const int quad = lane >> 4, l15 = lane & 15;
  const float sl = 0.125f * lam[h];

  // Q fragments (B-operand: n=l15 -> Q row, k=quad*8+j -> d), 2 m-tiles x 2 d-chunks
  FragU qf[2][2];
  #pragma unroll
  for (int mt = 0; mt < 2; ++mt){
    const bfu* qrow = qb + ((size_t)(b*S_LEN + i0 + w*32 + mt*16 + l15)*H_NUM + h)*DH;
    qf[mt][0].u = *(const uint4*)(qrow + quad*8);
    qf[mt][1].u = *(const uint4*)(qrow + 32 + quad*8);
  }

  const bfu* kbase = kb + ((size_t)b*S_LEN*H_NUM + h)*DH;     // + j*D_DIM + d
  const bfu* vbase = vt + (size_t)(b*H_NUM + h)*DH*S_LEN;     // + d*S_LEN + j

  f32x4 Oacc[2][4];    // O^T: rows d (quad*4+r per 16-tile), col m=l15
  #pragma unroll
  for (int mt = 0; mt < 2; ++mt)
    #pragma unroll
    for (int dt = 0; dt < 4; ++dt){ f32x4 zz = {0.f,0.f,0.f,0.f}; Oacc[mt][dt] = zz; }
  float m_[2] = {-1e30f, -1e30f}, l_[2] = {0.f, 0.f};

  for (int j0 = 0; j0 < S_LEN; j0 += 64){
    // K A-frags (rows j, k=d) and V^T A-frags (rows d, k=j) straight from global
    FragU kf[4][2], vf[2][4];
    #pragma unroll
    for (int jt = 0; jt < 4; ++jt){
      const bfu* kr = kbase + (size_t)(j0 + jt*16 + l15)*D_DIM + quad*8;
      kf[jt][0].u = *(const uint4*)kr;
      kf[jt][1].u = *(const uint4*)(kr + 32);
    }
    #pragma unroll
    for (int jt2 = 0; jt2 < 2; ++jt2)
      #pragma unroll
      for (int dt = 0; dt < 4; ++dt)
        vf[jt2][dt].u = *(const uint4*)(vbase + (size_t)(dt*16 + l15)*S_LEN + j0 + jt2*32 + quad*8);

    // S^T tiles: D[j][m], rows j=jt*16+quad*4+r, col m=l15
    f32x4 s[2][4];
    #pragma unroll
    for (int jt = 0; jt < 4; ++jt){
      #pragma unroll
      for (int mt = 0; mt < 2; ++mt){
        f32x4 zz = {0.f,0.f,0.f,0.f};
        zz = __builtin_amdgcn_mfma_f32_16x16x32_bf16(kf[jt][0].f, qf[mt][0].f, zz, 0, 0, 0);
        zz = __builtin_amdgcn_mfma_f32_16x16x32_bf16(kf[jt][1].f, qf[mt][1].f, zz, 0, 0, 0);
        #pragma unroll
        for (int r = 0; r < 4; ++r) zz[r] *= sl;
        s[mt][jt] = zz;
      }
    }

    float a2[2];
    #pragma unroll
    for (int mt = 0; mt < 2; ++mt){
      // in-lane max over this lane's 16 j's, then 2 cross-quad shuffles
      float mx = fmaxf(fmaxf(fmaxf(s[mt][0][0],s[mt][0][1]),fmaxf(s[mt][0][2],s[mt][0][3])),
                       fmaxf(fmaxf(s[mt][1][0],s[mt][1][1]),fmaxf(s[mt][1][2],s[mt][1][3])));
      mx = fmaxf(mx, fmaxf(fmaxf(fmaxf(s[mt][2][0],s[mt][2][1]),fmaxf(s[mt][2][2],s[mt][2][3])),
                           fmaxf(fmaxf(s[mt][3][0],s[mt][3][1]),fmaxf(s[mt][3][2],s[mt][3][3]))));
      mx = fmaxf(mx, __shfl_xor(mx, 16, 64));
      mx = fmaxf(mx, __shfl_xor(mx, 32, 64));
      float mn = fmaxf(m_[mt], mx);
      float a  = __expf(m_[mt] - mn);
      m_[mt] = mn;
      float ps = 0.f;
      #pragma unroll
      for (int jt = 0; jt < 4; ++jt){
        #pragma unroll
        for (int r = 0; r < 4; ++r){
          float p = __expf(s[mt][jt][r] - mn);
          s[mt][jt][r] = p;
          ps += p;
        }
      }
      ps += __shfl_xor(ps, 16, 64);
      ps += __shfl_xor(ps, 32, 64);
      l_[mt] = l_[mt]*a + ps;
      a2[mt] = a;
      // P (row-major per lane) -> per-wave LDS, b64 writes
      #pragma unroll
      for (int jt = 0; jt < 4; ++jt){
        uint2 pk;
        pk.x = (unsigned)f2bf(s[mt][jt][0]) | ((unsigned)f2bf(s[mt][jt][1]) << 16);
        pk.y = (unsigned)f2bf(s[mt][jt][2]) | ((unsigned)f2bf(s[mt][jt][3]) << 16);
        *(uint2*)&Ps[w][mt][l15][jt*16 + quad*4] = pk;
      }
      // rescale O^T by per-lane alpha
      #pragma unroll
      for (int dt = 0; dt < 4; ++dt)
        #pragma unroll
        for (int r = 0; r < 4; ++r) Oacc[mt][dt][r] *= a;
    }

    // PV: O^T[d][m] += V^T[d][j] · P[m][j]
    #pragma unroll
    for (int jt2 = 0; jt2 < 2; ++jt2){
      FragU pf0, pf1;
      pf0.u = *(const uint4*)&Ps[w][0][l15][jt2*32 + quad*8];
      pf1.u = *(const uint4*)&Ps[w][1][l15][jt2*32 + quad*8];
      #pragma unroll
      for (int dt = 0; dt < 4; ++dt){
        Oacc[0][dt] = __builtin_amdgcn_mfma_f32_16x16x32_bf16(vf[jt2][dt].f, pf0.f, Oacc[0][dt], 0, 0, 0);
        Oacc[1][dt] = __builtin_amdgcn_mfma_f32_16x16x32_bf16(vf[jt2][dt].f, pf1.f, Oacc[1][dt], 0, 0, 0);
      }
    }
  }

  #pragma unroll
  for (int mt = 0; mt < 2; ++mt){
    float inv = 1.f / l_[mt];
    bfu* orow = o + ((size_t)(b*S_LEN + i0 + w*32 + mt*16 + l15)*H_NUM + h)*DH;
    #pragma unroll
    for (int dt = 0; dt < 4; ++dt){
      ushort4 pk;
      pk.x = f2bf(Oacc[mt][dt][0]*inv); pk.y = f2bf(Oacc[mt][dt][1]*inv);
      pk.z = f2bf(Oacc[mt][dt][2]*inv); pk.w = f2bf(Oacc[mt][dt][3]*inv);
      *(ushort4*)(orow + dt*16 + quad*4) = pk;
    }
  }
}

// ---------------- GroupNorm partial sums: 256 blocks, f32 atomics ----------------
__global__ __launch_bounds__(256) void gn_part(const bfu* __restrict__ o, float* __restrict__ sums){
  const int bh = blockIdx.x >> 3, chunk = blockIdx.x & 7;
  const int b = bh >> 4, h = bh & 15;
  const bfu* base = o + ((size_t)(b*S_LEN + chunk*256)*H_NUM + h)*DH;
  float s1 = 0.f, s2 = 0.f;
  for (int u = threadIdx.x*4; u < 256*64; u += 256*4){
    int s = u >> 6, d = u & 63;
    ushort4 p = *(const ushort4*)(base + (size_t)s * D_DIM + d);
    float v0 = bf2f(p.x), v1 = bf2f(p.y), v2 = bf2f(p.z), v3 = bf2f(p.w);
    s1 += v0+v1+v2+v3; s2 += v0*v0+v1*v1+v2*v2+v3*v3;
  }
  s1 = wave_sum(s1); s2 = wave_sum(s2);
  __shared__ float r1[4], r2[4];
  int w = threadIdx.x >> 6, lane = threadIdx.x & 63;
  if (lane == 0){ r1[w] = s1; r2[w] = s2; }
  __syncthreads();
  if (threadIdx.x == 0){
    atomicAdd(&sums[bh*2+0], r1[0]+r1[1]+r1[2]+r1[3]);
    atomicAdd(&sums[bh*2+1], r2[0]+r2[1]+r2[2]+r2[3]);
  }
}

// ---------------- output projection MFMA with fused GroupNorm ----------------
__global__ __launch_bounds__(256) void oproj_mfma(
    const bfu* __restrict__ o, const bfu* __restrict__ wt,
    const void* __restrict__ bo, const float* __restrict__ sums,
    const void* __restrict__ gnw, const void* __restrict__ gnb,
    const int* __restrict__ flag, void* __restrict__ y)
{
  const int isf32 = flag[0];
  __shared__ __align__(16) ushort As[128][40];
  __shared__ __align__(16) ushort Bs[128][40];
  const int m0 = blockIdx.x * 128, n0 = blockIdx.y * 128;
  const int t = threadIdx.x, w = t >> 6, lane = t & 63;
  const int quad = lane >> 4, l15 = lane & 15;
  const int mbase = (w >> 1) * 64, nbase = (w & 1) * 64;
  const int srow = t >> 1, shalf = (t & 1) * 16;
  const float invN = 1.f / (float)(S_LEN * DH);

  f32x4 acc[4][4];
  #pragma unroll
  for (int i = 0; i < 4; ++i)
    #pragma unroll
    for (int j = 0; j < 4; ++j){ f32x4 zz = {0.f,0.f,0.f,0.f}; acc[i][j] = zz; }

  const int bB = m0 >> 11;   // batch uniform per block (128 | 2048)

  for (int k0 = 0; k0 < D_DIM; k0 += 32){
    { // A: normed o -> bf16
      const int kg = k0 + shalf;
      const int hh = kg >> 6;                  // uniform over 16 staged cols
      const float s1 = sums[(bB*H_NUM + hh)*2], s2 = sums[(bB*H_NUM + hh)*2 + 1];
      const float mu = s1 * invN;
      const float ri = rsqrtf(s2 * invN - mu*mu + EPS_GN);
      const bfu* asrc = o + (size_t)(m0 + srow) * D_DIM + kg;
      uint4 a0 = *(const uint4*)asrc, a1 = *(const uint4*)(asrc + 8);
      const bfu* ap = (const bfu*)&a0;
      bfu tmp[16];
      #pragma unroll
      for (int j = 0; j < 8; ++j)
        tmp[j] = f2bf((bf2f(ap[j]) - mu)*ri*ldx(gnw, kg+j, isf32) + ldx(gnb, kg+j, isf32));
      const bfu* ap2 = (const bfu*)&a1;
      #pragma unroll
      for (int j = 0; j < 8; ++j)
        tmp[8+j] = f2bf((bf2f(ap2[j]) - mu)*ri*ldx(gnw, kg+8+j, isf32) + ldx(gnb, kg+8+j, isf32));
      *(uint4*)&As[srow][shalf]     = *(const uint4*)tmp;
      *(uint4*)&As[srow][shalf + 8] = *(const uint4*)(tmp + 8);
    }
    {
      const bfu* bsrc = wt + (size_t)(n0 + srow) * D_DIM + k0 + shalf;
      uint4 b0 = *(const uint4*)bsrc, b1 = *(const uint4*)(bsrc + 8);
      *(uint4*)&Bs[srow][shalf]     = b0;  *(uint4*)&Bs[srow][shalf + 8] = b1;
    }
    __syncthreads();
    FragU af[4], bf[4];
    #pragma unroll
    for (int mt = 0; mt < 4; ++mt) af[mt].u = *(const uint4*)&As[mbase + mt*16 + l15][quad*8];
    #pragma unroll
    for (int nt = 0; nt < 4; ++nt) bf[nt].u = *(const uint4*)&Bs[nbase + nt*16 + l15][quad*8];
    #pragma unroll
    for (int mt = 0; mt < 4; ++mt)
      #pragma unroll
      for (int nt = 0; nt < 4; ++nt)
        acc[mt][nt] = __builtin_amdgcn_mfma_f32_16x16x32_bf16(af[mt].f, bf[nt].f, acc[mt][nt], 0, 0, 0);
    __syncthreads();
  }

  #pragma unroll
  for (int mt = 0; mt < 4; ++mt){
    const int mrow = m0 + mbase + mt*16 + quad*4;
    #pragma unroll
    for (int nt = 0; nt < 4; ++nt){
      const int n = n0 + nbase + nt*16 + l15;
      const float bn = ldx(bo, n, isf32);
      #pragma unroll
      for (int r = 0; r < 4; ++r){
        float val = acc[mt][nt][r] + bn;
        if (isf32) ((float*)y)[(size_t)(mrow + r) * D_DIM + n] = val;
        else       ((bfu*)y)[(size_t)(mrow + r) * D_DIM + n] = f2bf(val);
      }
    }
  }
}

extern "C" void kernel_launch(void* const* d_in, const int* in_sizes, int n_in,
                              void* d_out, int out_size, void* d_ws, size_t ws_size,
                              hipStream_t stream)
{
  const void* x   = d_in[0];
  const void* Wq  = d_in[1];
  const void* bq  = d_in[2];
  const void* Wk  = d_in[3];
  const void* bk  = d_in[4];
  const void* Wv  = d_in[5];
  const void* bv  = d_in[6];
  const void* Wo  = d_in[7];
  const void* bo  = d_in[8];
  const void* lq1 = d_in[9];
  const void* lk1 = d_in[10];
  const void* lq2 = d_in[11];
  const void* lk2 = d_in[12];
  const void* gnw = d_in[13];
  const void* gnb = d_in[14];

  float* ws   = (float*)d_ws;
  int*   flag = (int*)d_ws;   // ws[0]
  float* lam  = ws + 16;      // 16 floats
  float* sums = ws + 48;      // 64 floats (32 bh x {s1,s2})

  const size_t MB = 1u << 20;
  char* base = (char*)d_ws + 4096;
  bfu* xb = (bfu*)(base);             // 8 MB
  bfu* wt = (bfu*)(base + 8*MB);      // 8 MB (Wq^T, Wk^T, Wv^T, Wo^T)
  bfu* qb = (bfu*)(base + 16*MB);     // 8 MB
  bfu* kb = (bfu*)(base + 24*MB);     // 8 MB
  bfu* vt = (bfu*)(base + 32*MB);     // 8 MB  [B,H,DH,S]
  bfu* ob = (bfu*)(base + 40*MB);     // 8 MB

  lambda_kernel<<<1, 64, 0, stream>>>(lq1, lk1, lq2, lk2, (const unsigned int*)gnw, flag, lam, sums);
  prep_all<<<3072, 256, 0, stream>>>(x, Wq, Wk, Wv, Wo, flag, xb, wt);
  qkv_mfma<<<dim3(32, 8, 3), 256, 0, stream>>>(xb, wt, bq, bk, bv, flag, qb, kb, vt);
  attn_mfma<<<dim3(16, 16, 2), 256, 0, stream>>>(qb, kb, vt, lam, ob);
  gn_part<<<256, 256, 0, stream>>>(ob, sums);
  oproj_mfma<<<dim3(32, 8), 256, 0, stream>>>(ob, wt + (size_t)3*D_DIM*D_DIM, bo, sums, gnw, gnb, flag, d_out);
}